// Round 1
// baseline (811.803 us; speedup 1.0000x reference)
//
#include <hip/hip_runtime.h>
#include <hip/hip_bf16.h>
#include <stdint.h>

typedef __attribute__((ext_vector_type(4))) float f32x4;
typedef __attribute__((ext_vector_type(8))) short short8;

#define BM 128
#define BN 128
#define BK 32
#define DIM_S 4096
#define DIM_IN 1536
#define DIM_OUT 3072
#define LDK 40   // padded K stride in LDS (shorts): 80B rows -> 2-way bank alias (free)

__device__ __forceinline__ unsigned short f2bf(float f) {
    union { float f; unsigned u; } c; c.f = f;
    unsigned u = c.u;
    unsigned r = (u + 0x7FFFu + ((u >> 16) & 1u)) >> 16;  // RTNE
    return (unsigned short)r;
}

__global__ __launch_bounds__(256) void mol_gemm(
    const float* __restrict__ x, const int* __restrict__ orgidx,
    const float* __restrict__ weight, const float* __restrict__ bias,
    float* __restrict__ out)
{
    __shared__ __align__(16) unsigned short Alds[2][BM][LDK];  // [m][k]
    __shared__ __align__(16) unsigned short Blds[2][BN][LDK];  // [n][k] (transposed)

    const int tid  = threadIdx.x;
    const int lane = tid & 63;
    const int wave = tid >> 6;
    const int wr = wave >> 1, wc = wave & 1;

    const int row0 = blockIdx.x * BM;
    const int col0 = blockIdx.y * BN;

    const int batch = row0 / DIM_S;          // each 128-row block is within one batch
    const int org   = orgidx[batch];
    const float* __restrict__ W = weight + (size_t)org * DIM_IN * DIM_OUT;

    f32x4 acc[4][4] = {};

    auto stage = [&](int buf, int k0) {
        // A tile: BM x BK f32, float4 loads along k, cvt->bf16, ds_write_b64
        #pragma unroll
        for (int i = 0; i < 4; ++i) {
            int u  = tid + 256 * i;
            int r  = u >> 3;
            int c4 = (u & 7) * 4;
            const float4 v = *reinterpret_cast<const float4*>(
                x + (size_t)(row0 + r) * DIM_IN + k0 + c4);
            ushort4 p;
            p.x = f2bf(v.x); p.y = f2bf(v.y); p.z = f2bf(v.z); p.w = f2bf(v.w);
            *reinterpret_cast<ushort4*>(&Alds[buf][r][c4]) = p;
        }
        // B tile: BK x BN f32 global [k][n] -> LDS [n][k] bf16.
        // Per load instr: 64 lanes cover 64 consecutive n (coalesced 256B).
        const int n = tid & 127;
        #pragma unroll
        for (int i = 0; i < 4; ++i) {
            int kg = (tid >> 7) + 2 * i;     // 0..7
            const float* wp = W + (size_t)(k0 + kg * 4) * DIM_OUT + col0 + n;
            float f0 = wp[0 * DIM_OUT];
            float f1 = wp[1 * DIM_OUT];
            float f2 = wp[2 * DIM_OUT];
            float f3 = wp[3 * DIM_OUT];
            ushort4 p;
            p.x = f2bf(f0); p.y = f2bf(f1); p.z = f2bf(f2); p.w = f2bf(f3);
            *reinterpret_cast<ushort4*>(&Blds[buf][n][kg * 4]) = p;
        }
    };

    stage(0, 0);
    const int nk = DIM_IN / BK;   // 48
    const int kq = (lane >> 4) * 8;
    const int lr = lane & 15;

    for (int t = 0; t < nk; ++t) {
        __syncthreads();
        const int cur = t & 1;
        if (t + 1 < nk) stage(cur ^ 1, (t + 1) * BK);

        short8 a[4], b[4];
        #pragma unroll
        for (int mi = 0; mi < 4; ++mi)
            a[mi] = *reinterpret_cast<const short8*>(&Alds[cur][wr * 64 + mi * 16 + lr][kq]);
        #pragma unroll
        for (int ni = 0; ni < 4; ++ni)
            b[ni] = *reinterpret_cast<const short8*>(&Blds[cur][wc * 64 + ni * 16 + lr][kq]);

        #pragma unroll
        for (int mi = 0; mi < 4; ++mi) {
            #pragma unroll
            for (int ni = 0; ni < 4; ++ni)
                acc[mi][ni] = __builtin_amdgcn_mfma_f32_16x16x32_bf16(
                    a[mi], b[ni], acc[mi][ni], 0, 0, 0);
        }
    }

    // Epilogue: C/D layout col=lane&15, row=(lane>>4)*4+reg  (m89/m91 verified)
    const float* __restrict__ bptr = bias + (size_t)org * DIM_OUT;
    const int crow = (lane >> 4) * 4;
    const int ccol = lane & 15;
    #pragma unroll
    for (int ni = 0; ni < 4; ++ni) {
        const int gc = col0 + wc * 64 + ni * 16 + ccol;
        const float bv = bptr[gc];
        #pragma unroll
        for (int mi = 0; mi < 4; ++mi) {
            const int gr = row0 + wr * 64 + mi * 16 + crow;
            #pragma unroll
            for (int r = 0; r < 4; ++r)
                out[(size_t)(gr + r) * DIM_OUT + gc] = acc[mi][ni][r] + bv;
        }
    }
}

extern "C" void kernel_launch(void* const* d_in, const int* in_sizes, int n_in,
                              void* d_out, int out_size, void* d_ws, size_t ws_size,
                              hipStream_t stream)
{
    const float* x      = (const float*)d_in[0];
    const int*   orgidx = (const int*)d_in[1];
    const float* weight = (const float*)d_in[2];
    const float* bias   = (const float*)d_in[3];
    float* out = (float*)d_out;

    dim3 grid((8 * DIM_S) / BM, DIM_OUT / BN);   // (256, 24)
    mol_gemm<<<grid, dim3(256), 0, stream>>>(x, orgidx, weight, bias, out);
}

// Round 2
// 732.001 us; speedup vs baseline: 1.1090x; 1.1090x over previous
//
#include <hip/hip_runtime.h>
#include <hip/hip_bf16.h>
#include <stdint.h>

typedef __attribute__((ext_vector_type(4))) float f32x4;
typedef __attribute__((ext_vector_type(8))) short short8;

#define BM 128
#define BN 128
#define BK 32
#define DIM_S 4096
#define DIM_IN 1536
#define DIM_OUT 3072
#define LDK 40   // padded K stride in LDS (shorts): 80 B rows; b128 ops cover all 32 banks

union BF8 { unsigned short u[8]; short8 v; };

__device__ __forceinline__ unsigned short f2bf(float f) {
    __hip_bfloat16 h = __float2bfloat16(f);   // native v_cvt (pk-fusable)
    union { __hip_bfloat16 h; unsigned short u; } c; c.h = h;
    return c.u;
}

__global__ __launch_bounds__(256) void mol_gemm(
    const float* __restrict__ x, const int* __restrict__ orgidx,
    const float* __restrict__ weight, const float* __restrict__ bias,
    float* __restrict__ out)
{
    __shared__ __align__(16) unsigned short Alds[2][BM][LDK];  // [m][k]
    __shared__ __align__(16) unsigned short Blds[2][BN][LDK];  // [n][k] (transposed)

    const int tid  = threadIdx.x;
    const int lane = tid & 63;
    const int wave = tid >> 6;
    const int wr = wave >> 1, wc = wave & 1;

    // XCD-aware remap, col-fastest within each XCD chunk.
    // 6144 blocks = 8 XCDs x 768; 768 = 32 row-blocks (one batch) x 24 col-blocks.
    const int bid = blockIdx.x;
    const int id  = (bid & 7) * 768 + (bid >> 3);
    const int row0 = (id / 24) * BM;
    const int col0 = (id % 24) * BN;

    const int batch = row0 / DIM_S;
    const int org   = orgidx[batch];
    const float* __restrict__ W = weight + (size_t)org * DIM_IN * DIM_OUT;

    f32x4 acc[4][4] = {};

    // Staging geometry (per thread):
    //   A: 2 iters, row = (tid>>2)+64*i, k8 = (tid&3)*8  -> 2 float4 loads, 1 b128 write
    //   B: 2 iters, n = tid&127, g = (tid>>7)+2*j        -> 8 strided dword loads, 1 b128 write
    const int ar  = tid >> 2;
    const int ak8 = (tid & 3) * 8;
    const int bn  = tid & 127;
    const int bg0 = tid >> 7;

    const float* __restrict__ xbase = x + (size_t)row0 * DIM_IN;
    const float* __restrict__ wbase = W + col0 + bn;

    auto stage = [&](int buf, int k0) {
        #pragma unroll
        for (int i = 0; i < 2; ++i) {
            const int r = ar + 64 * i;
            const float* xp = xbase + (size_t)r * DIM_IN + k0 + ak8;
            const float4 v0 = *reinterpret_cast<const float4*>(xp);
            const float4 v1 = *reinterpret_cast<const float4*>(xp + 4);
            BF8 p;
            p.u[0] = f2bf(v0.x); p.u[1] = f2bf(v0.y);
            p.u[2] = f2bf(v0.z); p.u[3] = f2bf(v0.w);
            p.u[4] = f2bf(v1.x); p.u[5] = f2bf(v1.y);
            p.u[6] = f2bf(v1.z); p.u[7] = f2bf(v1.w);
            *reinterpret_cast<short8*>(&Alds[buf][r][ak8]) = p.v;
        }
        #pragma unroll
        for (int j = 0; j < 2; ++j) {
            const int g = bg0 + 2 * j;                       // k-block of 8
            const float* wp = wbase + (size_t)(k0 + 8 * g) * DIM_OUT;
            BF8 p;
            #pragma unroll
            for (int r = 0; r < 8; ++r)
                p.u[r] = f2bf(wp[(size_t)r * DIM_OUT]);      // coalesced across lanes
            *reinterpret_cast<short8*>(&Blds[buf][bn][8 * g]) = p.v;
        }
    };

    stage(0, 0);
    const int nk = DIM_IN / BK;   // 48
    const int kq = (lane >> 4) * 8;
    const int lr = lane & 15;

    for (int t = 0; t < nk; ++t) {
        __syncthreads();
        const int cur = t & 1;
        if (t + 1 < nk) stage(cur ^ 1, (t + 1) * BK);

        short8 a[4], b[4];
        #pragma unroll
        for (int mi = 0; mi < 4; ++mi)
            a[mi] = *reinterpret_cast<const short8*>(&Alds[cur][wr * 64 + mi * 16 + lr][kq]);
        #pragma unroll
        for (int ni = 0; ni < 4; ++ni)
            b[ni] = *reinterpret_cast<const short8*>(&Blds[cur][wc * 64 + ni * 16 + lr][kq]);

        #pragma unroll
        for (int mi = 0; mi < 4; ++mi) {
            #pragma unroll
            for (int ni = 0; ni < 4; ++ni)
                acc[mi][ni] = __builtin_amdgcn_mfma_f32_16x16x32_bf16(
                    a[mi], b[ni], acc[mi][ni], 0, 0, 0);
        }
    }

    // Epilogue: C/D layout col=lane&15, row=(lane>>4)*4+reg  (m89/m91 verified)
    const float* __restrict__ bptr = bias + (size_t)org * DIM_OUT;
    const int crow = (lane >> 4) * 4;
    const int ccol = lane & 15;
    #pragma unroll
    for (int ni = 0; ni < 4; ++ni) {
        const int gc = col0 + wc * 64 + ni * 16 + ccol;
        const float bv = bptr[gc];
        #pragma unroll
        for (int mi = 0; mi < 4; ++mi) {
            const int gr = row0 + wr * 64 + mi * 16 + crow;
            #pragma unroll
            for (int r = 0; r < 4; ++r)
                out[(size_t)(gr + r) * DIM_OUT + gc] = acc[mi][ni][r] + bv;
        }
    }
}

extern "C" void kernel_launch(void* const* d_in, const int* in_sizes, int n_in,
                              void* d_out, int out_size, void* d_ws, size_t ws_size,
                              hipStream_t stream)
{
    const float* x      = (const float*)d_in[0];
    const int*   orgidx = (const int*)d_in[1];
    const float* weight = (const float*)d_in[2];
    const float* bias   = (const float*)d_in[3];
    float* out = (float*)d_out;

    mol_gemm<<<dim3(6144), dim3(256), 0, stream>>>(x, orgidx, weight, bias, out);
}

// Round 3
// 569.751 us; speedup vs baseline: 1.4248x; 1.2848x over previous
//
#include <hip/hip_runtime.h>
#include <hip/hip_bf16.h>
#include <stdint.h>

typedef __attribute__((ext_vector_type(4))) float f32x4;
typedef __attribute__((ext_vector_type(8))) short short8;

#define DIM_S 4096
#define DIM_IN 1536
#define DIM_OUT 3072
#define NB 8
#define NORG 4

#define XB_ELEMS (NB * DIM_S * DIM_IN)      /* 50331648 */
#define WT_ELEMS (NORG * DIM_OUT * DIM_IN)  /* 18874368 */
#define WS_NEED ((size_t)(XB_ELEMS + WT_ELEMS) * 2)

#define BM 128
#define BN 128
#define BK 32

__device__ __forceinline__ unsigned short f2bf(float f) {
    union { __hip_bfloat16 h; unsigned short u; } c;
    c.h = __float2bfloat16(f);
    return c.u;
}

__device__ __forceinline__ void gload16(const void* g, void* l) {
    __builtin_amdgcn_global_load_lds(
        (const __attribute__((address_space(1))) unsigned int*)g,
        (__attribute__((address_space(3))) unsigned int*)l, 16, 0, 0);
}

// ---------- pass 1a: x f32 -> bf16 ----------
__global__ __launch_bounds__(256) void cvt_x(const float* __restrict__ x,
                                             unsigned short* __restrict__ xb) {
    const int nchunk = XB_ELEMS / 8;
    for (int c = blockIdx.x * 256 + threadIdx.x; c < nchunk; c += gridDim.x * 256) {
        const float4 v0 = *reinterpret_cast<const float4*>(x + (size_t)c * 8);
        const float4 v1 = *reinterpret_cast<const float4*>(x + (size_t)c * 8 + 4);
        union { unsigned short u[8]; short8 v; } p;
        p.u[0] = f2bf(v0.x); p.u[1] = f2bf(v0.y); p.u[2] = f2bf(v0.z); p.u[3] = f2bf(v0.w);
        p.u[4] = f2bf(v1.x); p.u[5] = f2bf(v1.y); p.u[6] = f2bf(v1.z); p.u[7] = f2bf(v1.w);
        *reinterpret_cast<short8*>(xb + (size_t)c * 8) = p.v;
    }
}

// ---------- pass 1b: W [org][K][N] f32 -> W^T [org][N][K] bf16 ----------
__global__ __launch_bounds__(256) void cvt_wt(const float* __restrict__ w,
                                              unsigned short* __restrict__ wt) {
    __shared__ unsigned short T[64][68];
    const int bid = blockIdx.x;            // NORG * 24 * 48
    const int org = bid / (24 * 48);
    const int rem = bid % (24 * 48);
    const int k0 = (rem / 48) * 64;
    const int n0 = (rem % 48) * 64;
    const float* __restrict__ wp = w + (size_t)org * DIM_IN * DIM_OUT;
    unsigned short* __restrict__ op = wt + (size_t)org * DIM_OUT * DIM_IN;
    const int t = threadIdx.x;
    #pragma unroll
    for (int i = 0; i < 4; ++i) {
        const int c = t + 256 * i;             // 0..1023
        const int kk = c >> 4, nq = (c & 15) * 4;
        const float4 v = *reinterpret_cast<const float4*>(
            wp + (size_t)(k0 + kk) * DIM_OUT + n0 + nq);
        ushort4 pv;
        pv.x = f2bf(v.x); pv.y = f2bf(v.y); pv.z = f2bf(v.z); pv.w = f2bf(v.w);
        *reinterpret_cast<ushort4*>(&T[kk][nq]) = pv;
    }
    __syncthreads();
    #pragma unroll
    for (int i = 0; i < 2; ++i) {
        const int c = t + 256 * i;             // 0..511
        const int n = c >> 3, k8 = (c & 7) * 8;
        union { unsigned short u[8]; short8 v; } p;
        #pragma unroll
        for (int j = 0; j < 8; ++j) p.u[j] = T[k8 + j][n];
        *reinterpret_cast<short8*>(op + (size_t)(n0 + n) * DIM_IN + k0 + k8) = p.v;
    }
}

// ---------- pass 2: bf16 GEMM, m97 structure + XOR swizzle ----------
// LDS tile [128 rows][32 k] bf16, linear (gload_lds). 16B chunk (r,q), q=0..3.
// Swizzle: position (r,q) holds logical (r, q ^ ((r>>1)&3)). Applied on the
// per-lane GLOBAL source (stage) and on the ds_read offset (both-sides, rule #21).
__global__ __launch_bounds__(256) void mol_gemm_bf(
    const unsigned short* __restrict__ xb, const int* __restrict__ orgidx,
    const unsigned short* __restrict__ wt, const float* __restrict__ bias,
    float* __restrict__ out)
{
    __shared__ __align__(16) unsigned short Alds[2][BM * BK];
    __shared__ __align__(16) unsigned short Blds[2][BN * BK];

    const int tid  = threadIdx.x;
    const int lane = tid & 63;
    const int wave = tid >> 6;
    const int wr = wave >> 1, wc = wave & 1;

    // XCD-aware remap: each XCD owns one batch (768 blocks), col-fastest.
    const int bid = blockIdx.x;
    const int id  = (bid & 7) * 768 + (bid >> 3);
    const int row0 = (id / 24) * BM;
    const int col0 = (id % 24) * BN;
    const int batch = row0 >> 12;
    const int org   = orgidx[batch];

    const unsigned short* __restrict__ A = xb + (size_t)row0 * DIM_IN;
    const unsigned short* __restrict__ B =
        wt + (size_t)org * DIM_OUT * DIM_IN + (size_t)col0 * DIM_IN;

    // staging geometry: chunk c = i*256 + tid; r = c>>2, q = c&3
    const int c0 = tid, c1 = 256 + tid;
    const int r0 = c0 >> 2, q0 = (c0 & 3) ^ ((r0 >> 1) & 3);
    const int r1 = c1 >> 2, q1 = (c1 & 3) ^ ((r1 >> 1) & 3);
    const unsigned short* a_src0 = A + (size_t)r0 * DIM_IN + q0 * 8;
    const unsigned short* a_src1 = A + (size_t)r1 * DIM_IN + q1 * 8;
    const unsigned short* b_src0 = B + (size_t)r0 * DIM_IN + q0 * 8;
    const unsigned short* b_src1 = B + (size_t)r1 * DIM_IN + q1 * 8;

    f32x4 acc[4][4] = {};

    const int nk = DIM_IN / BK;   // 48
    const int lr = lane & 15;
    const int q  = lane >> 4;     // k-quad 0..3

    // per-wave-uniform LDS dest bases (element offsets; lane adds 8 elems = 16B)
    const int dst0 = wave * 64 * 8;
    const int dst1 = (256 + wave * 64) * 8;

    #define STAGE(buf, k0)                                   \
        do {                                                 \
            gload16(a_src0 + (k0), &Alds[buf][dst0]);        \
            gload16(a_src1 + (k0), &Alds[buf][dst1]);        \
            gload16(b_src0 + (k0), &Blds[buf][dst0]);        \
            gload16(b_src1 + (k0), &Blds[buf][dst1]);        \
        } while (0)

    STAGE(0, 0);

    for (int t = 0; t < nk; ++t) {
        __syncthreads();
        const int cur = t & 1;
        if (t + 1 < nk) STAGE(cur ^ 1, (t + 1) * BK);

        short8 a[4], b[4];
        #pragma unroll
        for (int mi = 0; mi < 4; ++mi) {
            const int ar_ = wr * 64 + mi * 16 + lr;
            a[mi] = *reinterpret_cast<const short8*>(
                &Alds[cur][ar_ * 32 + ((q ^ ((ar_ >> 1) & 3)) << 3)]);
        }
        #pragma unroll
        for (int ni = 0; ni < 4; ++ni) {
            const int br_ = wc * 64 + ni * 16 + lr;
            b[ni] = *reinterpret_cast<const short8*>(
                &Blds[cur][br_ * 32 + ((q ^ ((br_ >> 1) & 3)) << 3)]);
        }

        #pragma unroll
        for (int mi = 0; mi < 4; ++mi)
            #pragma unroll
            for (int ni = 0; ni < 4; ++ni)
                acc[mi][ni] = __builtin_amdgcn_mfma_f32_16x16x32_bf16(
                    a[mi], b[ni], acc[mi][ni], 0, 0, 0);
    }

    // Epilogue: C/D layout col=lane&15, row=(lane>>4)*4+reg (m89/m91 verified)
    const float* __restrict__ bptr = bias + (size_t)org * DIM_OUT;
    const int crow = (lane >> 4) * 4;
    const int ccol = lane & 15;
    #pragma unroll
    for (int ni = 0; ni < 4; ++ni) {
        const int gc = col0 + wc * 64 + ni * 16 + ccol;
        const float bv = bptr[gc];
        #pragma unroll
        for (int mi = 0; mi < 4; ++mi) {
            const int gr = row0 + wr * 64 + mi * 16 + crow;
            #pragma unroll
            for (int r = 0; r < 4; ++r)
                out[(size_t)(gr + r) * DIM_OUT + gc] = acc[mi][ni][r] + bv;
        }
    }
    #undef STAGE
}

// ---------- fallback (R2 kernel) if ws too small ----------
#define LDK 40
union BF8 { unsigned short u[8]; short8 v; };

__global__ __launch_bounds__(256) void mol_gemm_fb(
    const float* __restrict__ x, const int* __restrict__ orgidx,
    const float* __restrict__ weight, const float* __restrict__ bias,
    float* __restrict__ out)
{
    __shared__ __align__(16) unsigned short Alds[2][BM][LDK];
    __shared__ __align__(16) unsigned short Blds[2][BN][LDK];

    const int tid  = threadIdx.x;
    const int lane = tid & 63;
    const int wave = tid >> 6;
    const int wr = wave >> 1, wc = wave & 1;

    const int bid = blockIdx.x;
    const int id  = (bid & 7) * 768 + (bid >> 3);
    const int row0 = (id / 24) * BM;
    const int col0 = (id % 24) * BN;

    const int batch = row0 / DIM_S;
    const int org   = orgidx[batch];
    const float* __restrict__ W = weight + (size_t)org * DIM_IN * DIM_OUT;

    f32x4 acc[4][4] = {};
    const int ar  = tid >> 2;
    const int ak8 = (tid & 3) * 8;
    const int bn  = tid & 127;
    const int bg0 = tid >> 7;
    const float* __restrict__ xbase = x + (size_t)row0 * DIM_IN;
    const float* __restrict__ wbase = W + col0 + bn;

    auto stage = [&](int buf, int k0) {
        #pragma unroll
        for (int i = 0; i < 2; ++i) {
            const int r = ar + 64 * i;
            const float* xp = xbase + (size_t)r * DIM_IN + k0 + ak8;
            const float4 v0 = *reinterpret_cast<const float4*>(xp);
            const float4 v1 = *reinterpret_cast<const float4*>(xp + 4);
            BF8 p;
            p.u[0] = f2bf(v0.x); p.u[1] = f2bf(v0.y);
            p.u[2] = f2bf(v0.z); p.u[3] = f2bf(v0.w);
            p.u[4] = f2bf(v1.x); p.u[5] = f2bf(v1.y);
            p.u[6] = f2bf(v1.z); p.u[7] = f2bf(v1.w);
            *reinterpret_cast<short8*>(&Alds[buf][r][ak8]) = p.v;
        }
        #pragma unroll
        for (int j = 0; j < 2; ++j) {
            const int g = bg0 + 2 * j;
            const float* wp = wbase + (size_t)(k0 + 8 * g) * DIM_OUT;
            BF8 p;
            #pragma unroll
            for (int r = 0; r < 8; ++r) p.u[r] = f2bf(wp[(size_t)r * DIM_OUT]);
            *reinterpret_cast<short8*>(&Blds[buf][bn][8 * g]) = p.v;
        }
    };

    stage(0, 0);
    const int nk = DIM_IN / BK;
    const int kq = (lane >> 4) * 8;
    const int lr = lane & 15;

    for (int t = 0; t < nk; ++t) {
        __syncthreads();
        const int cur = t & 1;
        if (t + 1 < nk) stage(cur ^ 1, (t + 1) * BK);
        short8 a[4], b[4];
        #pragma unroll
        for (int mi = 0; mi < 4; ++mi)
            a[mi] = *reinterpret_cast<const short8*>(&Alds[cur][wr * 64 + mi * 16 + lr][kq]);
        #pragma unroll
        for (int ni = 0; ni < 4; ++ni)
            b[ni] = *reinterpret_cast<const short8*>(&Blds[cur][wc * 64 + ni * 16 + lr][kq]);
        #pragma unroll
        for (int mi = 0; mi < 4; ++mi)
            #pragma unroll
            for (int ni = 0; ni < 4; ++ni)
                acc[mi][ni] = __builtin_amdgcn_mfma_f32_16x16x32_bf16(
                    a[mi], b[ni], acc[mi][ni], 0, 0, 0);
    }

    const float* __restrict__ bptr = bias + (size_t)org * DIM_OUT;
    const int crow = (lane >> 4) * 4;
    const int ccol = lane & 15;
    #pragma unroll
    for (int ni = 0; ni < 4; ++ni) {
        const int gc = col0 + wc * 64 + ni * 16 + ccol;
        const float bv = bptr[gc];
        #pragma unroll
        for (int mi = 0; mi < 4; ++mi) {
            const int gr = row0 + wr * 64 + mi * 16 + crow;
            #pragma unroll
            for (int r = 0; r < 4; ++r)
                out[(size_t)(gr + r) * DIM_OUT + gc] = acc[mi][ni][r] + bv;
        }
    }
}

extern "C" void kernel_launch(void* const* d_in, const int* in_sizes, int n_in,
                              void* d_out, int out_size, void* d_ws, size_t ws_size,
                              hipStream_t stream)
{
    const float* x      = (const float*)d_in[0];
    const int*   orgidx = (const int*)d_in[1];
    const float* weight = (const float*)d_in[2];
    const float* bias   = (const float*)d_in[3];
    float* out = (float*)d_out;

    if (ws_size >= WS_NEED) {
        unsigned short* xb  = (unsigned short*)d_ws;
        unsigned short* wtp = xb + XB_ELEMS;
        cvt_x<<<dim3(2048), dim3(256), 0, stream>>>(x, xb);
        cvt_wt<<<dim3(NORG * 24 * 48), dim3(256), 0, stream>>>(weight, wtp);
        mol_gemm_bf<<<dim3(6144), dim3(256), 0, stream>>>(xb, orgidx, wtp, bias, out);
    } else {
        mol_gemm_fb<<<dim3(6144), dim3(256), 0, stream>>>(x, orgidx, weight, bias, out);
    }
}

// Round 4
// 435.052 us; speedup vs baseline: 1.8660x; 1.3096x over previous
//
#include <hip/hip_runtime.h>
#include <hip/hip_bf16.h>
#include <stdint.h>

typedef __attribute__((ext_vector_type(4))) float f32x4;
typedef __attribute__((ext_vector_type(8))) short short8;

#define DIM_S 4096
#define DIM_IN 1536
#define DIM_OUT 3072
#define NB 8
#define NORG 4

#define XB_ELEMS (NB * DIM_S * DIM_IN)      /* 50331648 */
#define WT_ELEMS (NORG * DIM_OUT * DIM_IN)  /* 18874368 */
#define WS_NEED ((size_t)(XB_ELEMS + WT_ELEMS) * 2)

__device__ __forceinline__ unsigned short f2bf(float f) {
    union { __hip_bfloat16 h; unsigned short u; } c;
    c.h = __float2bfloat16(f);
    return c.u;
}

__device__ __forceinline__ void gload16(const void* g, void* l) {
    __builtin_amdgcn_global_load_lds(
        (const __attribute__((address_space(1))) unsigned int*)g,
        (__attribute__((address_space(3))) unsigned int*)l, 16, 0, 0);
}

// ---------- pass 1a: x f32 -> bf16 ----------
__global__ __launch_bounds__(256) void cvt_x(const float* __restrict__ x,
                                             unsigned short* __restrict__ xb) {
    const int nchunk = XB_ELEMS / 8;
    for (int c = blockIdx.x * 256 + threadIdx.x; c < nchunk; c += gridDim.x * 256) {
        const float4 v0 = *reinterpret_cast<const float4*>(x + (size_t)c * 8);
        const float4 v1 = *reinterpret_cast<const float4*>(x + (size_t)c * 8 + 4);
        union { unsigned short u[8]; short8 v; } p;
        p.u[0] = f2bf(v0.x); p.u[1] = f2bf(v0.y); p.u[2] = f2bf(v0.z); p.u[3] = f2bf(v0.w);
        p.u[4] = f2bf(v1.x); p.u[5] = f2bf(v1.y); p.u[6] = f2bf(v1.z); p.u[7] = f2bf(v1.w);
        *reinterpret_cast<short8*>(xb + (size_t)c * 8) = p.v;
    }
}

// ---------- pass 1b: W [org][K][N] f32 -> W^T [org][N][K] bf16 ----------
__global__ __launch_bounds__(256) void cvt_wt(const float* __restrict__ w,
                                              unsigned short* __restrict__ wt) {
    __shared__ unsigned short T[64][68];
    const int bid = blockIdx.x;
    const int org = bid / (24 * 48);
    const int rem = bid % (24 * 48);
    const int k0 = (rem / 48) * 64;
    const int n0 = (rem % 48) * 64;
    const float* __restrict__ wp = w + (size_t)org * DIM_IN * DIM_OUT;
    unsigned short* __restrict__ op = wt + (size_t)org * DIM_OUT * DIM_IN;
    const int t = threadIdx.x;
    #pragma unroll
    for (int i = 0; i < 4; ++i) {
        const int c = t + 256 * i;
        const int kk = c >> 4, nq = (c & 15) * 4;
        const float4 v = *reinterpret_cast<const float4*>(
            wp + (size_t)(k0 + kk) * DIM_OUT + n0 + nq);
        ushort4 pv;
        pv.x = f2bf(v.x); pv.y = f2bf(v.y); pv.z = f2bf(v.z); pv.w = f2bf(v.w);
        *reinterpret_cast<ushort4*>(&T[kk][nq]) = pv;
    }
    __syncthreads();
    #pragma unroll
    for (int i = 0; i < 2; ++i) {
        const int c = t + 256 * i;
        const int n = c >> 3, k8 = (c & 7) * 8;
        union { unsigned short u[8]; short8 v; } p;
        #pragma unroll
        for (int j = 0; j < 8; ++j) p.u[j] = T[k8 + j][n];
        *reinterpret_cast<short8*>(op + (size_t)(n0 + n) * DIM_IN + k0 + k8) = p.v;
    }
}

// ---------- pass 2: 256x256 8-phase bf16 GEMM ----------
// LDS: [buf][slot][256 rows][32 k] bf16; slots: 0=A-k0, 1=A-k1, 2=B-k0, 3=B-k1.
// Chunk (r, q'), q'=0..3 (16B): holds logical k-quad q = q' ^ s(r),
// s(r) = (r&3)^((r>>2)&1)  -> ds_read_b128 column reads hit each bank-quad
// exactly 2x (free, m136). gload_lds dest linear; source pre-swizzled.
__global__ __launch_bounds__(512, 2) void mol_gemm_8p(
    const unsigned short* __restrict__ xb, const int* __restrict__ orgidx,
    const unsigned short* __restrict__ wt, const float* __restrict__ bias,
    float* __restrict__ out)
{
    __shared__ __align__(16) unsigned short LDS[2][4][8192];  // 128 KiB

    const int tid  = threadIdx.x;
    const int lane = tid & 63;
    const int wave = tid >> 6;
    const int wr = wave >> 2;      // 0..1  (M half)
    const int wc = wave & 3;       // 0..3  (N quarter)
    const int l15 = lane & 15;
    const int q16 = lane >> 4;

    // XCD-aware remap: 1536 blocks = 8 XCDs x 192; 192 = 16 row x 12 col,
    // col-fastest -> each XCD owns exactly one batch (one organism).
    const int bid = blockIdx.x;
    const int id  = (bid & 7) * 192 + (bid >> 3);
    const int row0 = (id / 12) * 256;
    const int col0 = (id % 12) * 256;
    const int batch = row0 >> 12;
    const int org   = orgidx[batch];

    const unsigned short* __restrict__ Abase = xb + (size_t)row0 * DIM_IN;
    const unsigned short* __restrict__ Bbase =
        wt + (size_t)org * DIM_OUT * DIM_IN + (size_t)col0 * DIM_IN;

    // ---- staging source pointers (pre-swizzled global k-quad) ----
    const int rA = tid >> 2;                                   // 0..127
    const int qs = ((tid & 3) ^ (rA & 3) ^ ((rA >> 2) & 1)) * 8; // logical k elem
    const unsigned short* pA0 = Abase + (size_t)rA * DIM_IN + qs;
    const unsigned short* pA1 = Abase + (size_t)(128 + rA) * DIM_IN + qs;
    const unsigned short* pB0 = Bbase + (size_t)rA * DIM_IN + qs;
    const unsigned short* pB1 = Bbase + (size_t)(128 + rA) * DIM_IN + qs;

    // LDS dest bases (elements within a slot); HW adds lane*16B
    const int d0 = wave * 512;
    const int d1 = 4096 + wave * 512;

    // ---- ds_read byte offsets (per-lane, +1024*frag immediates) ----
    const int sw = (l15 & 3) ^ ((l15 >> 2) & 1);               // s(r) for this lane
    const int offA0 = ((wr * 128 + l15) * 32 + ((q16 ^ sw) << 3)) * 2;
    const int offB0 = ((wc * 64  + l15) * 32 + ((q16 ^ sw) << 3)) * 2;

    f32x4 acc[8][4] = {};
    short8 af[8], b0, b1;

#define STG(buf, slot, p0, p1, kofs) do {                      \
        gload16((p0) + (kofs), &LDS[buf][slot][d0]);           \
        gload16((p1) + (kofs), &LDS[buf][slot][d1]);           \
    } while (0)

#define RD_A(buf, kk) do {                                                  \
        const char* bA_ = (const char*)(&LDS[buf][kk][0]) + offA0;          \
        _Pragma("unroll")                                                   \
        for (int mi_ = 0; mi_ < 8; ++mi_)                                   \
            af[mi_] = *reinterpret_cast<const short8*>(bA_ + 1024 * mi_);   \
    } while (0)

#define RD_B(buf, kk, h) do {                                               \
        const char* bB_ = (const char*)(&LDS[buf][2 + (kk)][0]) + offB0;    \
        b0 = *reinterpret_cast<const short8*>(bB_ + 1024 * (2 * (h)));      \
        b1 = *reinterpret_cast<const short8*>(bB_ + 1024 * (2 * (h) + 1));  \
    } while (0)

#define MM(h) do {                                                          \
        __builtin_amdgcn_s_setprio(1);                                      \
        _Pragma("unroll")                                                   \
        for (int mi_ = 0; mi_ < 8; ++mi_) {                                 \
            acc[mi_][2*(h)]   = __builtin_amdgcn_mfma_f32_16x16x32_bf16(    \
                af[mi_], b0, acc[mi_][2*(h)], 0, 0, 0);                     \
            acc[mi_][2*(h)+1] = __builtin_amdgcn_mfma_f32_16x16x32_bf16(    \
                af[mi_], b1, acc[mi_][2*(h)+1], 0, 0, 0);                   \
        }                                                                   \
        __builtin_amdgcn_s_setprio(0);                                      \
    } while (0)

#define BAR do { __builtin_amdgcn_s_barrier();                              \
                 asm volatile("" ::: "memory"); } while (0)
#define WAIT8 asm volatile("s_waitcnt vmcnt(8)" ::: "memory")

    // ---- prologue: stage tile0 (buf0) fully + tile1 k0 halves (buf1) ----
    STG(0, 0, pA0, pA1, 0);    // A(0,k0)
    STG(0, 2, pB0, pB1, 0);    // B(0,k0)
    STG(0, 1, pA0, pA1, 32);   // A(0,k1)
    STG(0, 3, pB0, pB1, 32);   // B(0,k1)
    STG(1, 0, pA0, pA1, 64);   // A(1,k0)
    STG(1, 2, pB0, pB1, 64);   // B(1,k0)
    WAIT8;                     // tile0-k0 landed; 4 stage-ops (8 loads) in flight
    BAR;

    int kA = 96, kB = 96;      // next stage offsets: A(1,k1)/B(1,k1)

    // Per tile t (buf): P1(k0,h0) stage A(t+1,k1)->obuf; P2(k0,h1) stage
    // B(t+1,k1)->obuf, vmcnt(8); P3(k1,h0) stage A(t+2,k0)->buf;
    // P4(k1,h1) stage B(t+2,k0)->buf, vmcnt(8). Slot write-after-read is
    // covered by the P2/P4-end barriers (all reads of a phase are consumed
    // by its MFMAs, hence complete before that phase's barrier).
#define TILE(buf, obuf) do {                                                   \
        RD_A(buf, 0); RD_B(buf, 0, 0);                                         \
        STG(obuf, 1, pA0, pA1, kA); if (kA < 1504) kA += 32;                   \
        MM(0); BAR;                                                            \
        RD_B(buf, 0, 1);                                                       \
        STG(obuf, 3, pB0, pB1, kB); if (kB < 1504) kB += 32;                   \
        MM(1); WAIT8; BAR;                                                     \
        RD_A(buf, 1); RD_B(buf, 1, 0);                                         \
        STG(buf, 0, pA0, pA1, kA); if (kA < 1504) kA += 32;                    \
        MM(0); BAR;                                                            \
        RD_B(buf, 1, 1);                                                       \
        STG(buf, 2, pB0, pB1, kB); if (kB < 1504) kB += 32;                    \
        MM(1); WAIT8; BAR;                                                     \
    } while (0)

    #pragma unroll 1
    for (int i = 0; i < 12; ++i) {   // 24 K-tiles, 2 per iter
        TILE(0, 1);
        TILE(1, 0);
    }

    // ---- epilogue: bias + store f32 ----
    const float* __restrict__ bptr = bias + (size_t)org * DIM_OUT;
    const int crow = q16 * 4;
    const int ccol = l15;
    #pragma unroll
    for (int ni = 0; ni < 4; ++ni) {
        const int gc = col0 + wc * 64 + ni * 16 + ccol;
        const float bv = bptr[gc];
        #pragma unroll
        for (int mi = 0; mi < 8; ++mi) {
            const int gr = row0 + wr * 128 + mi * 16 + crow;
            #pragma unroll
            for (int r = 0; r < 4; ++r)
                out[(size_t)(gr + r) * DIM_OUT + gc] = acc[mi][ni][r] + bv;
        }
    }
#undef STG
#undef RD_A
#undef RD_B
#undef MM
#undef BAR
#undef WAIT8
#undef TILE
}

// ---------- fallback (R2 kernel) if ws too small ----------
#define BM 128
#define BN 128
#define BK 32
#define LDK 40
union BF8 { unsigned short u[8]; short8 v; };

__global__ __launch_bounds__(256) void mol_gemm_fb(
    const float* __restrict__ x, const int* __restrict__ orgidx,
    const float* __restrict__ weight, const float* __restrict__ bias,
    float* __restrict__ out)
{
    __shared__ __align__(16) unsigned short Alds[2][BM][LDK];
    __shared__ __align__(16) unsigned short Blds[2][BN][LDK];

    const int tid  = threadIdx.x;
    const int lane = tid & 63;
    const int wave = tid >> 6;
    const int wr = wave >> 1, wc = wave & 1;

    const int bid = blockIdx.x;
    const int id  = (bid & 7) * 768 + (bid >> 3);
    const int row0 = (id / 24) * BM;
    const int col0 = (id % 24) * BN;

    const int batch = row0 / DIM_S;
    const int org   = orgidx[batch];
    const float* __restrict__ W = weight + (size_t)org * DIM_IN * DIM_OUT;

    f32x4 acc[4][4] = {};
    const int ar  = tid >> 2;
    const int ak8 = (tid & 3) * 8;
    const int bn  = tid & 127;
    const int bg0 = tid >> 7;
    const float* __restrict__ xbase = x + (size_t)row0 * DIM_IN;
    const float* __restrict__ wbase = W + col0 + bn;

    auto stage = [&](int buf, int k0) {
        #pragma unroll
        for (int i = 0; i < 2; ++i) {
            const int r = ar + 64 * i;
            const float* xp = xbase + (size_t)r * DIM_IN + k0 + ak8;
            const float4 v0 = *reinterpret_cast<const float4*>(xp);
            const float4 v1 = *reinterpret_cast<const float4*>(xp + 4);
            BF8 p;
            p.u[0] = f2bf(v0.x); p.u[1] = f2bf(v0.y);
            p.u[2] = f2bf(v0.z); p.u[3] = f2bf(v0.w);
            p.u[4] = f2bf(v1.x); p.u[5] = f2bf(v1.y);
            p.u[6] = f2bf(v1.z); p.u[7] = f2bf(v1.w);
            *reinterpret_cast<short8*>(&Alds[buf][r][ak8]) = p.v;
        }
        #pragma unroll
        for (int j = 0; j < 2; ++j) {
            const int g = bg0 + 2 * j;
            const float* wp = wbase + (size_t)(k0 + 8 * g) * DIM_OUT;
            BF8 p;
            #pragma unroll
            for (int r = 0; r < 8; ++r) p.u[r] = f2bf(wp[(size_t)r * DIM_OUT]);
            *reinterpret_cast<short8*>(&Blds[buf][bn][8 * g]) = p.v;
        }
    };

    stage(0, 0);
    const int nk = DIM_IN / BK;
    const int kq = (lane >> 4) * 8;
    const int lr = lane & 15;

    for (int t = 0; t < nk; ++t) {
        __syncthreads();
        const int cur = t & 1;
        if (t + 1 < nk) stage(cur ^ 1, (t + 1) * BK);
        short8 a[4], b[4];
        #pragma unroll
        for (int mi = 0; mi < 4; ++mi)
            a[mi] = *reinterpret_cast<const short8*>(&Alds[cur][wr * 64 + mi * 16 + lr][kq]);
        #pragma unroll
        for (int ni = 0; ni < 4; ++ni)
            b[ni] = *reinterpret_cast<const short8*>(&Blds[cur][wc * 64 + ni * 16 + lr][kq]);
        #pragma unroll
        for (int mi = 0; mi < 4; ++mi)
            #pragma unroll
            for (int ni = 0; ni < 4; ++ni)
                acc[mi][ni] = __builtin_amdgcn_mfma_f32_16x16x32_bf16(
                    a[mi], b[ni], acc[mi][ni], 0, 0, 0);
    }

    const float* __restrict__ bptr = bias + (size_t)org * DIM_OUT;
    const int crow = (lane >> 4) * 4;
    const int ccol = lane & 15;
    #pragma unroll
    for (int ni = 0; ni < 4; ++ni) {
        const int gc = col0 + wc * 64 + ni * 16 + ccol;
        const float bv = bptr[gc];
        #pragma unroll
        for (int mi = 0; mi < 4; ++mi) {
            const int gr = row0 + wr * 64 + mi * 16 + crow;
            #pragma unroll
            for (int r = 0; r < 4; ++r)
                out[(size_t)(gr + r) * DIM_OUT + gc] = acc[mi][ni][r] + bv;
        }
    }
}

extern "C" void kernel_launch(void* const* d_in, const int* in_sizes, int n_in,
                              void* d_out, int out_size, void* d_ws, size_t ws_size,
                              hipStream_t stream)
{
    const float* x      = (const float*)d_in[0];
    const int*   orgidx = (const int*)d_in[1];
    const float* weight = (const float*)d_in[2];
    const float* bias   = (const float*)d_in[3];
    float* out = (float*)d_out;

    if (ws_size >= WS_NEED) {
        unsigned short* xbp = (unsigned short*)d_ws;
        unsigned short* wtp = xbp + XB_ELEMS;
        cvt_x<<<dim3(2048), dim3(256), 0, stream>>>(x, xbp);
        cvt_wt<<<dim3(NORG * 24 * 48), dim3(256), 0, stream>>>(weight, wtp);
        mol_gemm_8p<<<dim3(1536), dim3(512), 0, stream>>>(xbp, orgidx, wtp, bias, out);
    } else {
        mol_gemm_fb<<<dim3(6144), dim3(256), 0, stream>>>(x, orgidx, weight, bias, out);
    }
}